// Round 4
// baseline (128.557 us; speedup 1.0000x reference)
//
#include <hip/hip_runtime.h>

#define SEQ_LEN   512
#define PRED_LEN  96
#define PATCH_LEN 16
#define STRIDE    8
#define NQ        4
#define NUM_PATCHES 63
#define BB        32
#define MM        128
#define NROWS     (BB*MM)            // 4096
#define FAN_IN    (NUM_PATCHES*NQ)   // 252

// ---------------- kernel 0: build the full 16x16 circuit unitary ----------------
// Output layout (column-major): u[k*32 + i] = Re U[i][k], u[k*32+16+i] = Im U[i][k]
__global__ __launch_bounds__(128) void build_u_kernel(const float* __restrict__ w,
                                                      float* __restrict__ u) {
    __shared__ float Ur[16][17], Ui[16][17];
    const int tid = threadIdx.x;
    const int col = tid & 15;
    const int pr  = tid >> 4;        // pair index 0..7

    for (int idx = tid; idx < 256; idx += 128) {
        int i = idx >> 4, j = idx & 15;
        Ur[i][j] = (i == j) ? 1.f : 0.f;
        Ui[i][j] = 0.f;
    }

    for (int l = 0; l < 3; ++l) {
        for (int wi = 0; wi < 4; ++wi) {
            const float* g = w + (l*4 + wi)*3;
            float phi = g[0], th = g[1], om = g[2];
            float ct = cosf(0.5f*th), st = sinf(0.5f*th);
            float ap = 0.5f*(phi+om), am = 0.5f*(phi-om);
            float m00r =  cosf(ap)*ct, m00i = -sinf(ap)*ct;
            float m01r = -cosf(am)*st, m01i = -sinf(am)*st;
            float m10r =  cosf(am)*st, m10i = -sinf(am)*st;
            float m11r =  cosf(ap)*ct, m11i =  sinf(ap)*ct;
            int bp = 3 - wi;                                  // wire wi <-> bit 3-wi
            int i0 = ((pr >> bp) << (bp+1)) | (pr & ((1<<bp)-1));
            int i1 = i0 | (1 << bp);
            __syncthreads();
            float a_r = Ur[i0][col], a_i = Ui[i0][col];
            float b_r = Ur[i1][col], b_i = Ui[i1][col];
            Ur[i0][col] = m00r*a_r - m00i*a_i + m01r*b_r - m01i*b_i;
            Ui[i0][col] = m00r*a_i + m00i*a_r + m01r*b_i + m01i*b_r;
            Ur[i1][col] = m10r*a_r - m10i*a_i + m11r*b_r - m11i*b_i;
            Ui[i1][col] = m10r*a_i + m10i*a_r + m11r*b_i + m11i*b_r;
        }
        int r = (l % 3) + 1;                                  // ranges: 1,2,3
        for (int wi = 0; wi < 4; ++wi) {
            int cm = 8 >> wi, tm = 8 >> ((wi + r) & 3);
            __syncthreads();
            if (pr < 4) {
                int i = cm, prr = pr;
                int rem = 15 & ~cm & ~tm;
                for (int bpos = 0; bpos < 4; ++bpos)
                    if (rem & (1 << bpos)) { if (prr & 1) i |= (1 << bpos); prr >>= 1; }
                int j = i | tm;
                float tr = Ur[i][col], ti = Ui[i][col];
                Ur[i][col] = Ur[j][col]; Ui[i][col] = Ui[j][col];
                Ur[j][col] = tr;         Ui[j][col] = ti;
            }
        }
    }
    __syncthreads();
    for (int idx = tid; idx < 256; idx += 128) {
        int k = idx >> 4, i = idx & 15;
        u[k*32 + i]      = Ur[i][k];
        u[k*32 + 16 + i] = Ui[i][k];
    }
}

// ---------------- kernel 1: encode = U matvec + PauliZ ----------------
// 1D grid 1008 = 63 p x 16 yq, XCD-chunked: XCD k handles b in [4k, 4k+4)
__global__ __launch_bounds__(256) void encode_kernel(const float* __restrict__ x,
                                                     const float* __restrict__ u,
                                                     float* __restrict__ enc_t) {
    const int L   = blockIdx.x;            // 0..1007
    const int xcd = L & 7;
    const int idx = L >> 3;                // 0..125
    const int p   = idx % 63;
    const int yq  = xcd * 2 + idx / 63;    // 0..15
    const int row = yq * 256 + threadIdx.x;
    const int b   = row >> 7;
    const int m   = row & 127;
    const float* xp = x + b * (SEQ_LEN * MM) + p * STRIDE * MM + m;

    float v[16];
    float tot = 0.f;
    #pragma unroll
    for (int k = 0; k < 16; ++k) {
        v[k] = xp[k * MM] + 1e-6f;
        tot = fmaf(v[k], v[k], tot);        // ||v||^2 (= ||Uv||^2, U unitary)
    }
    float yr[16], yi[16];
    #pragma unroll
    for (int i = 0; i < 16; ++i) { yr[i] = 0.f; yi[i] = 0.f; }
    #pragma unroll
    for (int k = 0; k < 16; ++k) {
        const float* uc = u + k * 32;       // uniform -> s_load
        #pragma unroll
        for (int i = 0; i < 16; ++i) {
            yr[i] = fmaf(uc[i],      v[k], yr[i]);
            yi[i] = fmaf(uc[16 + i], v[k], yi[i]);
        }
    }
    float z0 = 0.f, z1 = 0.f, z2 = 0.f, z3 = 0.f;
    #pragma unroll
    for (int i = 0; i < 16; ++i) {
        float pr2 = yr[i]*yr[i] + yi[i]*yi[i];
        z0 += (i & 8) ? -pr2 : pr2;
        z1 += (i & 4) ? -pr2 : pr2;
        z2 += (i & 2) ? -pr2 : pr2;
        z3 += (i & 1) ? -pr2 : pr2;
    }
    const float invt = 1.0f / tot;
    float* e = enc_t + p * 4 * NROWS + row;
    e[0*NROWS] = z0 * invt;
    e[1*NROWS] = z1 * invt;
    e[2*NROWS] = z2 * invt;
    e[3*NROWS] = z3 * invt;
}

// ---------------- kernel 2: fused head + skip GEMM ----------------
// block = 256: 64 m-lanes x 4 K-split WAVES (ks = wave id -> weight loads scalar).
// Explicit 21/32-deep load batches for memory-level parallelism.
#define TT 12
__global__ __launch_bounds__(256) void head_kernel(const float* __restrict__ x,
                                                   const float* __restrict__ enc_t,
                                                   const float* __restrict__ head_w,
                                                   const float* __restrict__ head_b,
                                                   const float* __restrict__ skip_w,
                                                   const float* __restrict__ skip_b,
                                                   float* __restrict__ out) {
    const int tid = threadIdx.x;
    const int m   = tid & 63;
    const int ks  = __builtin_amdgcn_readfirstlane(tid >> 6);   // wave id 0..3

    // bijective XCD-chunk swizzle: XCD k gets 4 consecutive b's
    const int L = blockIdx.x;                 // 0..511
    const int T = (L & 7) * 64 + (L >> 3);
    const int b    = T >> 4;                  // 0..31
    const int tile = (T >> 1) & 7;            // 0..7
    const int mh   = T & 1;                   // 0..1
    const int t0   = tile * TT;
    const int row  = b * MM + mh * 64 + m;

    float acc[TT];
    #pragma unroll
    for (int tt = 0; tt < TT; ++tt) acc[tt] = 0.f;

    // enc part: 63 j per wave, 3 batches of 21 loads
    {
        const float* e = enc_t + row;
        const int j0 = ks * 63;
        #pragma unroll 1
        for (int bb = 0; bb < 3; ++bb) {
            float ev[21];
            #pragma unroll
            for (int i = 0; i < 21; ++i) ev[i] = e[(j0 + bb*21 + i) * NROWS];
            #pragma unroll
            for (int i = 0; i < 21; ++i) {
                const int j = j0 + bb*21 + i;
                #pragma unroll
                for (int tt = 0; tt < TT; ++tt)
                    acc[tt] = fmaf(ev[i], head_w[(t0+tt)*FAN_IN + j], acc[tt]);
            }
        }
    }
    // skip part: 128 l per wave, 4 batches of 32 loads
    {
        const float* xr = x + b * (SEQ_LEN * MM) + mh * 64 + m;
        const int l0 = ks * 128;
        #pragma unroll 1
        for (int bb = 0; bb < 4; ++bb) {
            float xv[32];
            #pragma unroll
            for (int i = 0; i < 32; ++i) xv[i] = xr[(l0 + bb*32 + i) * MM];
            #pragma unroll
            for (int i = 0; i < 32; ++i) {
                const int l = l0 + bb*32 + i;
                #pragma unroll
                for (int tt = 0; tt < TT; ++tt)
                    acc[tt] = fmaf(xv[i], skip_w[(t0+tt)*SEQ_LEN + l], acc[tt]);
            }
        }
    }

    __shared__ float red[TT][256];
    #pragma unroll
    for (int tt = 0; tt < TT; ++tt) red[tt][tid] = acc[tt];
    __syncthreads();

    if (tid < 64) {
        float* o = out + b * (PRED_LEN * MM) + t0 * MM + mh * 64 + m;
        #pragma unroll
        for (int tt = 0; tt < TT; ++tt) {
            float s = red[tt][m] + red[tt][m+64] + red[tt][m+128] + red[tt][m+192];
            o[tt * MM] = s + head_b[t0+tt] + skip_b[t0+tt];
        }
    }
}

extern "C" void kernel_launch(void* const* d_in, const int* in_sizes, int n_in,
                              void* d_out, int out_size, void* d_ws, size_t ws_size,
                              hipStream_t stream) {
    const float* x       = (const float*)d_in[0];
    const float* weights = (const float*)d_in[1];
    const float* head_w  = (const float*)d_in[2];
    const float* head_b  = (const float*)d_in[3];
    const float* skip_w  = (const float*)d_in[4];
    const float* skip_b  = (const float*)d_in[5];
    float* out = (float*)d_out;

    float* u     = (float*)d_ws;              // 512 floats
    float* enc_t = (float*)d_ws + 1024;       // 252*4096 floats = 4.13 MB

    hipLaunchKernelGGL(build_u_kernel, dim3(1), dim3(128), 0, stream, weights, u);
    hipLaunchKernelGGL(encode_kernel, dim3(63*16), dim3(256), 0, stream,
                       x, u, enc_t);
    hipLaunchKernelGGL(head_kernel, dim3(512), dim3(256), 0, stream,
                       x, enc_t, head_w, head_b, skip_w, skip_b, out);
}

// Round 5
// 105.311 us; speedup vs baseline: 1.2207x; 1.2207x over previous
//
#include <hip/hip_runtime.h>

#define SEQ_LEN   512
#define PRED_LEN  96
#define PATCH_LEN 16
#define STRIDE    8
#define NQ        4
#define NUM_PATCHES 63
#define BB        32
#define MM        128
#define NROWS     (BB*MM)            // 4096
#define FAN_IN    (NUM_PATCHES*NQ)   // 252

// ---------------- kernel 0: build the full 16x16 circuit unitary ----------------
// Output layout (column-major): u[k*32 + i] = Re U[i][k], u[k*32+16+i] = Im U[i][k]
__global__ __launch_bounds__(128) void build_u_kernel(const float* __restrict__ w,
                                                      float* __restrict__ u) {
    __shared__ float Ur[16][17], Ui[16][17];
    const int tid = threadIdx.x;
    const int col = tid & 15;
    const int pr  = tid >> 4;        // pair index 0..7

    for (int idx = tid; idx < 256; idx += 128) {
        int i = idx >> 4, j = idx & 15;
        Ur[i][j] = (i == j) ? 1.f : 0.f;
        Ui[i][j] = 0.f;
    }

    for (int l = 0; l < 3; ++l) {
        for (int wi = 0; wi < 4; ++wi) {
            const float* g = w + (l*4 + wi)*3;
            float phi = g[0], th = g[1], om = g[2];
            float ct = cosf(0.5f*th), st = sinf(0.5f*th);
            float ap = 0.5f*(phi+om), am = 0.5f*(phi-om);
            float m00r =  cosf(ap)*ct, m00i = -sinf(ap)*ct;
            float m01r = -cosf(am)*st, m01i = -sinf(am)*st;
            float m10r =  cosf(am)*st, m10i = -sinf(am)*st;
            float m11r =  cosf(ap)*ct, m11i =  sinf(ap)*ct;
            int bp = 3 - wi;                                  // wire wi <-> bit 3-wi
            int i0 = ((pr >> bp) << (bp+1)) | (pr & ((1<<bp)-1));
            int i1 = i0 | (1 << bp);
            __syncthreads();
            float a_r = Ur[i0][col], a_i = Ui[i0][col];
            float b_r = Ur[i1][col], b_i = Ui[i1][col];
            Ur[i0][col] = m00r*a_r - m00i*a_i + m01r*b_r - m01i*b_i;
            Ui[i0][col] = m00r*a_i + m00i*a_r + m01r*b_i + m01i*b_r;
            Ur[i1][col] = m10r*a_r - m10i*a_i + m11r*b_r - m11i*b_i;
            Ui[i1][col] = m10r*a_i + m10i*a_r + m11r*b_i + m11i*b_r;
        }
        int r = (l % 3) + 1;                                  // ranges: 1,2,3
        for (int wi = 0; wi < 4; ++wi) {
            int cm = 8 >> wi, tm = 8 >> ((wi + r) & 3);
            __syncthreads();
            if (pr < 4) {
                int i = cm, prr = pr;
                int rem = 15 & ~cm & ~tm;
                for (int bpos = 0; bpos < 4; ++bpos)
                    if (rem & (1 << bpos)) { if (prr & 1) i |= (1 << bpos); prr >>= 1; }
                int j = i | tm;
                float tr = Ur[i][col], ti = Ui[i][col];
                Ur[i][col] = Ur[j][col]; Ui[i][col] = Ui[j][col];
                Ur[j][col] = tr;         Ui[j][col] = ti;
            }
        }
    }
    __syncthreads();
    for (int idx = tid; idx < 256; idx += 128) {
        int k = idx >> 4, i = idx & 15;
        u[k*32 + i]      = Ur[i][k];
        u[k*32 + 16 + i] = Ui[i][k];
    }
}

// ---------------- kernel 1: encode = U matvec + PauliZ ----------------
// 1D grid 1008 = 63 p x 16 yq, XCD-chunked: XCD k handles b in [4k, 4k+4)
__global__ __launch_bounds__(256) void encode_kernel(const float* __restrict__ x,
                                                     const float* __restrict__ u,
                                                     float* __restrict__ enc_t) {
    const int L   = blockIdx.x;            // 0..1007
    const int xcd = L & 7;
    const int idx = L >> 3;                // 0..125
    const int p   = idx % 63;
    const int yq  = xcd * 2 + idx / 63;    // 0..15
    const int row = yq * 256 + threadIdx.x;
    const int b   = row >> 7;
    const int m   = row & 127;
    const float* xp = x + b * (SEQ_LEN * MM) + p * STRIDE * MM + m;

    float v[16];
    float tot = 0.f;
    #pragma unroll
    for (int k = 0; k < 16; ++k) {
        v[k] = xp[k * MM] + 1e-6f;
        tot = fmaf(v[k], v[k], tot);        // ||v||^2 (= ||Uv||^2, U unitary)
    }
    float yr[16], yi[16];
    #pragma unroll
    for (int i = 0; i < 16; ++i) { yr[i] = 0.f; yi[i] = 0.f; }
    #pragma unroll
    for (int k = 0; k < 16; ++k) {
        const float* uc = u + k * 32;       // uniform -> s_load
        #pragma unroll
        for (int i = 0; i < 16; ++i) {
            yr[i] = fmaf(uc[i],      v[k], yr[i]);
            yi[i] = fmaf(uc[16 + i], v[k], yi[i]);
        }
    }
    float z0 = 0.f, z1 = 0.f, z2 = 0.f, z3 = 0.f;
    #pragma unroll
    for (int i = 0; i < 16; ++i) {
        float pr2 = yr[i]*yr[i] + yi[i]*yi[i];
        z0 += (i & 8) ? -pr2 : pr2;
        z1 += (i & 4) ? -pr2 : pr2;
        z2 += (i & 2) ? -pr2 : pr2;
        z3 += (i & 1) ? -pr2 : pr2;
    }
    const float invt = 1.0f / tot;
    float* e = enc_t + p * 4 * NROWS + row;
    e[0*NROWS] = z0 * invt;
    e[1*NROWS] = z1 * invt;
    e[2*NROWS] = z2 * invt;
    e[3*NROWS] = z3 * invt;
}

// ---------------- kernel 2: fused head + skip GEMM ----------------
// block = 256: 64 row-lanes x 4 K-split waves. Weights loaded as wave-uniform
// float4 (s_load_dwordx4, k-contiguous) -> 6 SMEM reqs per 4-k chunk per wave.
// grid = 1024: 32 b x 2 mh x 16 t-tiles (TT=6), XCD-chunked on b.
#define TT 6
__global__ __launch_bounds__(256) void head_kernel(const float* __restrict__ x,
                                                   const float* __restrict__ enc_t,
                                                   const float* __restrict__ head_w,
                                                   const float* __restrict__ head_b,
                                                   const float* __restrict__ skip_w,
                                                   const float* __restrict__ skip_b,
                                                   float* __restrict__ out) {
    const int tid  = threadIdx.x;
    const int lane = tid & 63;
    const int ks   = __builtin_amdgcn_readfirstlane(tid >> 6);  // wave id 0..3

    // bijective XCD-chunk swizzle: XCD k gets b in [4k, 4k+4)
    const int L = blockIdx.x;                 // 0..1023
    const int T = (L & 7) * 128 + (L >> 3);
    const int b    = T >> 5;                  // 0..31
    const int mh   = (T >> 4) & 1;            // 0..1
    const int tile = T & 15;                  // 0..15
    const int t0   = tile * TT;
    const int row  = b * MM + mh * 64 + lane;

    float acc[TT];
    #pragma unroll
    for (int tt = 0; tt < TT; ++tt) acc[tt] = 0.f;

    // enc part: 63 4-k chunks split 16/16/16/15 across waves
    {
        const float* e = enc_t + row;
        #pragma unroll 4
        for (int cb = 0; cb < 16; ++cb) {
            const int c = ks * 16 + cb;
            if (c < 63) {
                const int j0 = c * 4;
                float a0 = e[(j0+0)*NROWS], a1 = e[(j0+1)*NROWS];
                float a2 = e[(j0+2)*NROWS], a3 = e[(j0+3)*NROWS];
                #pragma unroll
                for (int tt = 0; tt < TT; ++tt) {
                    const float4 wv = *(const float4*)(head_w + (t0+tt)*FAN_IN + j0);
                    acc[tt] = fmaf(a0, wv.x, acc[tt]);
                    acc[tt] = fmaf(a1, wv.y, acc[tt]);
                    acc[tt] = fmaf(a2, wv.z, acc[tt]);
                    acc[tt] = fmaf(a3, wv.w, acc[tt]);
                }
            }
        }
    }
    // skip part: 128 4-k chunks split 32 per wave
    {
        const float* xr = x + b * (SEQ_LEN * MM) + mh * 64 + lane;
        #pragma unroll 4
        for (int cb = 0; cb < 32; ++cb) {
            const int l0 = (ks * 32 + cb) * 4;
            float a0 = xr[(l0+0)*MM], a1 = xr[(l0+1)*MM];
            float a2 = xr[(l0+2)*MM], a3 = xr[(l0+3)*MM];
            #pragma unroll
            for (int tt = 0; tt < TT; ++tt) {
                const float4 wv = *(const float4*)(skip_w + (t0+tt)*SEQ_LEN + l0);
                acc[tt] = fmaf(a0, wv.x, acc[tt]);
                acc[tt] = fmaf(a1, wv.y, acc[tt]);
                acc[tt] = fmaf(a2, wv.z, acc[tt]);
                acc[tt] = fmaf(a3, wv.w, acc[tt]);
            }
        }
    }

    __shared__ float red[TT][256];
    #pragma unroll
    for (int tt = 0; tt < TT; ++tt) red[tt][tid] = acc[tt];
    __syncthreads();

    if (tid < 64) {
        float* o = out + b * (PRED_LEN * MM) + t0 * MM + mh * 64 + lane;
        #pragma unroll
        for (int tt = 0; tt < TT; ++tt) {
            float s = red[tt][lane] + red[tt][lane+64] + red[tt][lane+128] + red[tt][lane+192];
            o[tt * MM] = s + head_b[t0+tt] + skip_b[t0+tt];
        }
    }
}

extern "C" void kernel_launch(void* const* d_in, const int* in_sizes, int n_in,
                              void* d_out, int out_size, void* d_ws, size_t ws_size,
                              hipStream_t stream) {
    const float* x       = (const float*)d_in[0];
    const float* weights = (const float*)d_in[1];
    const float* head_w  = (const float*)d_in[2];
    const float* head_b  = (const float*)d_in[3];
    const float* skip_w  = (const float*)d_in[4];
    const float* skip_b  = (const float*)d_in[5];
    float* out = (float*)d_out;

    float* u     = (float*)d_ws;              // 512 floats
    float* enc_t = (float*)d_ws + 1024;       // 252*4096 floats = 4.13 MB

    hipLaunchKernelGGL(build_u_kernel, dim3(1), dim3(128), 0, stream, weights, u);
    hipLaunchKernelGGL(encode_kernel, dim3(63*16), dim3(256), 0, stream,
                       x, u, enc_t);
    hipLaunchKernelGGL(head_kernel, dim3(1024), dim3(256), 0, stream,
                       x, enc_t, head_w, head_b, skip_w, skip_b, out);
}